// Round 15
// baseline (3084.150 us; speedup 1.0000x reference)
//
#include <hip/hip_runtime.h>
#include <cstdint>
#include <cstddef>

#define NFILT 40
#define NBINS 257
#define HID   64
#define BB    64      // batch
#define TT    2000    // time
#define GATES 256     // 4*HID
#define MTOT  (BB*TT) // 128000 rows

typedef float float2v __attribute__((ext_vector_type(2)));

// packed dual-FMA: one VOP3P instruction = 2 independent fp32 FMAs
__device__ __forceinline__ float2v pk_fma(float2v a, float2v b, float2v c) {
  asm("v_pk_fma_f32 %0, %1, %2, %0" : "+v"(c) : "v"(a), "v"(b));
  return c;
}

// ---------- activations ----------
__device__ __forceinline__ float sigm(float x) {
  return 1.0f / (1.0f + __expf(-x));
}

// quad butterfly via DPP (VALU pipe, no LDS) (numerically verified R5/R11/R12)
__device__ __forceinline__ float bfly1(float x) {
  int i = __builtin_amdgcn_mov_dpp(__float_as_int(x), 0xB1, 0xF, 0xF, true); // quad_perm [1,0,3,2]
  return x + __int_as_float(i);
}
__device__ __forceinline__ float bfly2(float x) {
  int i = __builtin_amdgcn_mov_dpp(__float_as_int(x), 0x4E, 0xF, 0xF, true); // quad_perm [2,3,0,1]
  return x + __int_as_float(i);
}
// quad broadcast: every lane gets lane q's value (quad_perm [q,q,q,q])
#define QB(x, ctrl) __int_as_float(__builtin_amdgcn_mov_dpp(__float_as_int(x), (ctrl), 0xF, 0xF, true))

// ---------- kernel 1: build fbank (40x257) + per-filter support bounds ----------
__global__ void k_fbank(const float* __restrict__ binpoints,
                        float* __restrict__ fbank,
                        int* __restrict__ lohi /*[2*NFILT]*/) {
  __shared__ float b[NFILT + 2];
  int tid = threadIdx.x;
  if (tid < NFILT + 2) b[tid] = binpoints[tid];
  __syncthreads();
  if (tid < NFILT) {
    if (tid == NFILT - 1) { lohi[tid] = 0; lohi[NFILT + tid] = 0; }
    else {
      int lo = (int)floorf(b[tid]);
      int hi = (int)floorf(b[tid + 2]);
      if (lo < 0) lo = 0;
      if (hi > NBINS) hi = NBINS;
      lohi[tid] = lo; lohi[NFILT + tid] = hi;
    }
  }
  for (int idx = tid; idx < NFILT * NBINS; idx += blockDim.x) {
    int f = idx / NBINS, i = idx - f * NBINS;
    float bj = b[f], bj1 = b[f + 1], bj2 = b[f + 2];
    float fb0 = floorf(bj), fb1 = floorf(bj1), fb2 = floorf(bj2);
    float fi = (float)i;
    bool rise = (fi >= fb0) && (fi < fb1);
    bool fall = (fi >= fb1) && (fi < fb2);
    float d1 = bj1 - bj;  d1 = (d1 > 0.f) ? d1 : 1.f;
    float d2 = bj2 - bj1; d2 = (d2 > 0.f) ? d2 : 1.f;
    float rv = (fi - bj)  / (d1 * d1);
    float fv = (bj2 - fi) / (d2 * d2);
    float v = fall ? fv : (rise ? rv : 0.f);
    if (f == NFILT - 1) v = 0.f;
    fbank[idx] = v;
  }
}

// ---------- kernel 2: featurize, 4 rows per 256-thread block (one wave each) ----------
__global__ __launch_bounds__(256) void k_feat(const float* __restrict__ x,
                                              const float* __restrict__ fbank,
                                              const int* __restrict__ lohi,
                                              float* __restrict__ h0) {
  const int wv   = threadIdx.x >> 6;
  const int lane = threadIdx.x & 63;
  const int bt   = blockIdx.x * 4 + wv;
  __shared__ float xs[4][NBINS];
  const float* xr = x + (size_t)bt * NBINS;
  for (int i = lane; i < NBINS; i += 64) xs[wv][i] = xr[i];
  __syncthreads();
  if (lane < NFILT) {
    float acc = 0.f;
    int lo = lohi[lane], hi = lohi[NFILT + lane];
    for (int i = lo; i < hi; ++i) acc = fmaf(xs[wv][i], fbank[lane * NBINS + i], acc);
    float val = (lane == 0) ? xs[wv][0] : acc;
    h0[(size_t)bt * NFILT + lane] = logf(val + 1e-10f);
  }
}

// ---------- kernel 3: fp32 GEMM, 128x64 tile, 8x4 micro, pk_fma inner loop ----------
// Rows paired into float2 accumulators: h-pairs come free from ds_read_b128
// result registers; w broadcast into a pair (4 movs/kk). 32 fmac -> 16 pk_fma.
template <int K, int BK>
__global__ __launch_bounds__(256) void k_gemm(const float* __restrict__ Hm,   // [MTOT][K]
                                              const float* __restrict__ W,    // [2][256][K]
                                              const float* __restrict__ bih,  // [2][256]
                                              const float* __restrict__ bhh,  // [2][256]
                                              float* __restrict__ pre) {      // [2][MTOT][256]
  constexpr int BM = 128, BN = 64;
  __shared__ float Hs[BK][BM + 4];
  __shared__ float Ws[BK][BN + 4];
  const int d  = blockIdx.z;
  const int m0 = blockIdx.x * BM;
  const int g0 = blockIdx.y * BN;
  const int tid = threadIdx.x;
  const int tx = tid & 15, ty = tid >> 4;

  float2v acc2[4][4];   // [row-pair p: rows 2p,2p+1][col j]
#pragma unroll
  for (int p = 0; p < 4; ++p)
#pragma unroll
    for (int j = 0; j < 4; ++j) acc2[p][j] = (float2v){0.f, 0.f};

  for (int k0 = 0; k0 < K; k0 += BK) {
    constexpr int HL = BM * BK / 256;
#pragma unroll
    for (int i = 0; i < HL; ++i) {
      int flat = tid + i * 256;
      int r = flat / BK, kk = flat - r * BK;
      Hs[kk][r] = Hm[(size_t)(m0 + r) * K + k0 + kk];
    }
    constexpr int WL = BN * BK / 256;
#pragma unroll
    for (int i = 0; i < WL; ++i) {
      int flat = tid + i * 256;
      int r = flat / BK, kk = flat - r * BK;
      Ws[kk][r] = W[((size_t)d * GATES + g0 + r) * K + k0 + kk];
    }
    __syncthreads();
#pragma unroll
    for (int kk = 0; kk < BK; ++kk) {
      const float4 wv  = *(const float4*)&Ws[kk][tx * 4];
      const float4 hv0 = *(const float4*)&Hs[kk][ty * 8];
      const float4 hv1 = *(const float4*)&Hs[kk][ty * 8 + 4];
      float2v hp[4];
      hp[0].x = hv0.x; hp[0].y = hv0.y;
      hp[1].x = hv0.z; hp[1].y = hv0.w;
      hp[2].x = hv1.x; hp[2].y = hv1.y;
      hp[3].x = hv1.z; hp[3].y = hv1.w;
      const float wc[4] = {wv.x, wv.y, wv.z, wv.w};
#pragma unroll
      for (int j = 0; j < 4; ++j) {
        float2v wb; wb.x = wc[j]; wb.y = wc[j];
#pragma unroll
        for (int p = 0; p < 4; ++p)
          acc2[p][j] = pk_fma(hp[p], wb, acc2[p][j]);
      }
    }
    __syncthreads();
  }

  const int gcol = g0 + tx * 4;
  const float4 bi = *(const float4*)&bih[d * GATES + gcol];
  const float4 bh = *(const float4*)&bhh[d * GATES + gcol];
  const float bx = bi.x + bh.x, by = bi.y + bh.y, bz = bi.z + bh.z, bw = bi.w + bh.w;
#pragma unroll
  for (int p = 0; p < 4; ++p) {
    size_t m = (size_t)(m0 + ty * 8 + 2 * p);
    float4 o0 = {acc2[p][0].x + bx, acc2[p][1].x + by, acc2[p][2].x + bz, acc2[p][3].x + bw};
    float4 o1 = {acc2[p][0].y + bx, acc2[p][1].y + by, acc2[p][2].y + bz, acc2[p][3].y + bw};
    *(float4*)&pre[((size_t)d * MTOT + m) * GATES + gcol] = o0;
    *(float4*)&pre[((size_t)d * MTOT + m + 1) * GATES + gcol] = o1;
  }
}

// ---------- kernel 4: recurrent LSTM, quad-per-unit, pk_fma matvec ----------
// R12/R14 configuration (proven 800 us, VGPR 132) with the matvec switched to
// v_pk_fma_f32: 64 scalar fmac (128 cyc issue, 16-deep chains) -> 32 pk_fma
// (64 cyc issue, 8-deep chains) + 4 horizontal adds. Weights held as PINNED
// float2 pairs so the asm operands are natively pair-aligned (no repack movs).
// All structure unchanged: 4 waves/block, 1 wave/SIMD, waves_per_eu(1,1),
// quad DPP butterfly + single activation + quad broadcasts, parity
// double-buffered hs, raw asm "lgkmcnt(0); s_barrier" (no vmcnt drain).
__global__ __attribute__((amdgpu_waves_per_eu(1, 1)))
__launch_bounds__(256) void k_lstmq(const float* __restrict__ pre, // [2][B*T][256]
                                    const float* __restrict__ whh, // [2][256][64]
                                    float* __restrict__ hout,      // [B][T][128]
                                    float* __restrict__ out,       // [B][128]
                                    int final_layer) {
  const int b   = blockIdx.x;
  const int d   = blockIdx.y;
  const int tid = threadIdx.x;
  const int wl  = tid >> 6;          // wave 0..3
  const int l   = tid & 63;
  const int uu  = wl * 16 + (l >> 2); // hidden unit owned by this quad
  const int p   = l & 3;              // k-slice / gate index
  const int p16 = p * 16;

  __shared__ __align__(16) float hs[2][HID];   // parity double-buffered h

  // weights as pairs: wp[q][i] = (W[d][q*64+uu][16p+2i], W[d][q*64+uu][16p+2i+1])
  float2v wp[4][8];
#pragma unroll
  for (int q = 0; q < 4; ++q) {
    const float4* wr = (const float4*)(whh + ((size_t)d * GATES + q * HID + uu) * HID + p16);
#pragma unroll
    for (int c2 = 0; c2 < 4; ++c2) {
      const float4 t4 = wr[c2];
      wp[q][2 * c2].x     = t4.x; wp[q][2 * c2].y     = t4.y;
      wp[q][2 * c2 + 1].x = t4.z; wp[q][2 * c2 + 1].y = t4.w;
    }
  }
#pragma unroll
  for (int q = 0; q < 4; ++q)
#pragma unroll
    for (int i = 0; i < 8; ++i) asm volatile("" : "+v"(wp[q][i]));  // pin resident

  // per-lane activation constants: gate 2 (p==2) is tanh = 2*sigm(2x)-1
  const float sA = (p == 2) ? 2.f : 1.f;   // input scale
  const float aA = (p == 2) ? 2.f : 1.f;   // output scale
  const float aB = (p == 2) ? -1.f : 0.f;  // output bias
  const bool  p1 = (p & 1) != 0;
  const bool  p2 = (p & 2) != 0;

  if (tid < HID) { hs[0][tid] = 0.f; hs[1][tid] = 0.f; }
  float c = 0.f, sum = 0.f;
  __syncthreads();   // one-time full barrier

  const int t0 = d ? (TT - 1) : 0;
  const int dt = d ? -1 : 1;
  const float* pp = pre + ((size_t)d * MTOT + (size_t)b * TT + t0) * GATES + (p * HID + uu);
  const ptrdiff_t pstr = (ptrdiff_t)dt * GATES;

  float pf0 = pp[0], pf1 = pp[pstr], pf2 = pp[pstr * 2], pf3 = pp[pstr * 3];

#define GDOT(Q)                                                                 \
  ({ float2v acc_ = {0.f, 0.f};                                                 \
     acc_ = pk_fma(A0, wp[Q][0], acc_);                                         \
     acc_ = pk_fma(A1, wp[Q][1], acc_);                                         \
     acc_ = pk_fma(B0, wp[Q][2], acc_);                                         \
     acc_ = pk_fma(B1, wp[Q][3], acc_);                                         \
     acc_ = pk_fma(C0, wp[Q][4], acc_);                                         \
     acc_ = pk_fma(C1, wp[Q][5], acc_);                                         \
     acc_ = pk_fma(D0, wp[Q][6], acc_);                                         \
     acc_ = pk_fma(D1, wp[Q][7], acc_);                                         \
     acc_.x + acc_.y; })

#define LSTM_STEP(TK, PAR, PF)                                                  \
  do {                                                                          \
    const float4* h4 = (const float4*)&hs[PAR][p16];                            \
    const float4 hA = h4[0], hB = h4[1], hC = h4[2], hD = h4[3];                \
    float2v A0, A1, B0, B1, C0, C1, D0, D1;                                     \
    A0.x = hA.x; A0.y = hA.y; A1.x = hA.z; A1.y = hA.w;                         \
    B0.x = hB.x; B0.y = hB.y; B1.x = hB.z; B1.y = hB.w;                         \
    C0.x = hC.x; C0.y = hC.y; C1.x = hC.z; C1.y = hC.w;                         \
    D0.x = hD.x; D0.y = hD.y; D1.x = hD.z; D1.y = hD.w;                         \
    float a0 = GDOT(0);                                                         \
    float a1 = GDOT(1);                                                         \
    float a2 = GDOT(2);                                                         \
    float a3 = GDOT(3);                                                         \
    a0 = bfly2(bfly1(a0)); a1 = bfly2(bfly1(a1));                               \
    a2 = bfly2(bfly1(a2)); a3 = bfly2(bfly1(a3));                               \
    const float t02 = p2 ? a2 : a0;                                             \
    const float t13 = p2 ? a3 : a1;                                             \
    const float zsel = (p1 ? t13 : t02) + (PF);                                 \
    const float act = fmaf(sigm(zsel * sA), aA, aB);                            \
    const float ig = QB(act, 0x00), fg = QB(act, 0x55);                         \
    const float gg = QB(act, 0xAA), og = QB(act, 0xFF);                         \
    c = fmaf(fg, c, ig * gg);                                                   \
    const float tc = fmaf(sigm(2.f * c), 2.f, -1.f);                            \
    const float hvv = og * tc;                                                  \
    if (p == 0) hs[(PAR) ^ 1][uu] = hvv;                                        \
    asm volatile("s_waitcnt lgkmcnt(0)\n\ts_barrier" ::: "memory");             \
    if (final_layer) sum += hvv;                                                \
    else if (p == 0)                                                            \
      hout[((size_t)b * TT + (size_t)(t0 + dt * (TK))) * (2 * HID) + d * HID + uu] = hvv; \
  } while (0)

  for (int t = 0; t < TT; t += 4) {
    LSTM_STEP(t + 0, 0, pf0);
    { int ip = t + 4; if (ip >= TT) ip = 0; pf0 = pp[pstr * (ptrdiff_t)ip]; }
    LSTM_STEP(t + 1, 1, pf1);
    { int ip = t + 5; if (ip >= TT) ip = 0; pf1 = pp[pstr * (ptrdiff_t)ip]; }
    LSTM_STEP(t + 2, 0, pf2);
    { int ip = t + 6; if (ip >= TT) ip = 0; pf2 = pp[pstr * (ptrdiff_t)ip]; }
    LSTM_STEP(t + 3, 1, pf3);
    { int ip = t + 7; if (ip >= TT) ip = 0; pf3 = pp[pstr * (ptrdiff_t)ip]; }
  }
#undef LSTM_STEP
#undef GDOT

  if (final_layer && p == 0) out[b * (2 * HID) + d * HID + uu] = sum * (1.0f / (float)TT);
}

// ---------- launch ----------
extern "C" void kernel_launch(void* const* d_in, const int* in_sizes, int n_in,
                              void* d_out, int out_size, void* d_ws, size_t ws_size,
                              hipStream_t stream) {
  const float* x         = (const float*)d_in[0];
  const float* binpoints = (const float*)d_in[1];
  const float* w_ih[3] = {(const float*)d_in[2], (const float*)d_in[6],  (const float*)d_in[10]};
  const float* w_hh[3] = {(const float*)d_in[3], (const float*)d_in[7],  (const float*)d_in[11]};
  const float* b_ih[3] = {(const float*)d_in[4], (const float*)d_in[8],  (const float*)d_in[12]};
  const float* b_hh[3] = {(const float*)d_in[5], (const float*)d_in[9],  (const float*)d_in[13]};
  float* out = (float*)d_out;

  // workspace layout (~349 MB):
  //   pre  : 2*MTOT*256 f32 = 262,144,000 B
  //   Hbuf : MTOT*128 f32   =  65,536,000 B
  //   h0   : MTOT*40 f32    =  20,480,000 B
  //   fbank: 40*257 f32, lohi: 80 i32
  float* pre   = (float*)d_ws;
  float* Hbuf  = pre  + (size_t)2 * MTOT * GATES;
  float* h0    = Hbuf + (size_t)MTOT * 128;
  float* fbank = h0   + (size_t)MTOT * NFILT;
  int*   lohi  = (int*)(fbank + NFILT * NBINS);

  k_fbank<<<1, 256, 0, stream>>>(binpoints, fbank, lohi);
  k_feat<<<MTOT / 4, 256, 0, stream>>>(x, fbank, lohi, h0);

  // layer 0 (K=40)
  k_gemm<40, 40><<<dim3(MTOT / 128, GATES / 64, 2), 256, 0, stream>>>(h0, w_ih[0], b_ih[0], b_hh[0], pre);
  k_lstmq<<<dim3(BB, 2), 256, 0, stream>>>(pre, w_hh[0], Hbuf, out, 0);

  // layer 1 (K=128)
  k_gemm<128, 32><<<dim3(MTOT / 128, GATES / 64, 2), 256, 0, stream>>>(Hbuf, w_ih[1], b_ih[1], b_hh[1], pre);
  k_lstmq<<<dim3(BB, 2), 256, 0, stream>>>(pre, w_hh[1], Hbuf, out, 0);

  // layer 2 (K=128)
  k_gemm<128, 32><<<dim3(MTOT / 128, GATES / 64, 2), 256, 0, stream>>>(Hbuf, w_ih[2], b_ih[2], b_hh[2], pre);
  k_lstmq<<<dim3(BB, 2), 256, 0, stream>>>(pre, w_hh[2], Hbuf, out, 1);
}

// Round 16
// 2907.398 us; speedup vs baseline: 1.0608x; 1.0608x over previous
//
#include <hip/hip_runtime.h>
#include <cstdint>
#include <cstddef>

#define NFILT 40
#define NBINS 257
#define HID   64
#define BB    64      // batch
#define TT    2000    // time
#define GATES 256     // 4*HID
#define MTOT  (BB*TT) // 128000 rows

typedef float float2v __attribute__((ext_vector_type(2)));

// packed dual-FMA: one VOP3P instruction = 2 independent fp32 FMAs
__device__ __forceinline__ float2v pk_fma(float2v a, float2v b, float2v c) {
  asm("v_pk_fma_f32 %0, %1, %2, %0" : "+v"(c) : "v"(a), "v"(b));
  return c;
}

// ---------- activations ----------
__device__ __forceinline__ float sigm(float x) {
  return 1.0f / (1.0f + __expf(-x));
}

// quad butterfly via DPP (VALU pipe, no LDS) (numerically verified R5/R11/R12)
__device__ __forceinline__ float bfly1(float x) {
  int i = __builtin_amdgcn_mov_dpp(__float_as_int(x), 0xB1, 0xF, 0xF, true); // quad_perm [1,0,3,2]
  return x + __int_as_float(i);
}
__device__ __forceinline__ float bfly2(float x) {
  int i = __builtin_amdgcn_mov_dpp(__float_as_int(x), 0x4E, 0xF, 0xF, true); // quad_perm [2,3,0,1]
  return x + __int_as_float(i);
}
// quad broadcast: every lane gets lane q's value (quad_perm [q,q,q,q])
#define QB(x, ctrl) __int_as_float(__builtin_amdgcn_mov_dpp(__float_as_int(x), (ctrl), 0xF, 0xF, true))

// ---------- kernel 1: build fbank (40x257) + per-filter support bounds ----------
__global__ void k_fbank(const float* __restrict__ binpoints,
                        float* __restrict__ fbank,
                        int* __restrict__ lohi /*[2*NFILT]*/) {
  __shared__ float b[NFILT + 2];
  int tid = threadIdx.x;
  if (tid < NFILT + 2) b[tid] = binpoints[tid];
  __syncthreads();
  if (tid < NFILT) {
    if (tid == NFILT - 1) { lohi[tid] = 0; lohi[NFILT + tid] = 0; }
    else {
      int lo = (int)floorf(b[tid]);
      int hi = (int)floorf(b[tid + 2]);
      if (lo < 0) lo = 0;
      if (hi > NBINS) hi = NBINS;
      lohi[tid] = lo; lohi[NFILT + tid] = hi;
    }
  }
  for (int idx = tid; idx < NFILT * NBINS; idx += blockDim.x) {
    int f = idx / NBINS, i = idx - f * NBINS;
    float bj = b[f], bj1 = b[f + 1], bj2 = b[f + 2];
    float fb0 = floorf(bj), fb1 = floorf(bj1), fb2 = floorf(bj2);
    float fi = (float)i;
    bool rise = (fi >= fb0) && (fi < fb1);
    bool fall = (fi >= fb1) && (fi < fb2);
    float d1 = bj1 - bj;  d1 = (d1 > 0.f) ? d1 : 1.f;
    float d2 = bj2 - bj1; d2 = (d2 > 0.f) ? d2 : 1.f;
    float rv = (fi - bj)  / (d1 * d1);
    float fv = (bj2 - fi) / (d2 * d2);
    float v = fall ? fv : (rise ? rv : 0.f);
    if (f == NFILT - 1) v = 0.f;
    fbank[idx] = v;
  }
}

// ---------- kernel 2: featurize, 4 rows per 256-thread block (one wave each) ----------
__global__ __launch_bounds__(256) void k_feat(const float* __restrict__ x,
                                              const float* __restrict__ fbank,
                                              const int* __restrict__ lohi,
                                              float* __restrict__ h0) {
  const int wv   = threadIdx.x >> 6;
  const int lane = threadIdx.x & 63;
  const int bt   = blockIdx.x * 4 + wv;
  __shared__ float xs[4][NBINS];
  const float* xr = x + (size_t)bt * NBINS;
  for (int i = lane; i < NBINS; i += 64) xs[wv][i] = xr[i];
  __syncthreads();
  if (lane < NFILT) {
    float acc = 0.f;
    int lo = lohi[lane], hi = lohi[NFILT + lane];
    for (int i = lo; i < hi; ++i) acc = fmaf(xs[wv][i], fbank[lane * NBINS + i], acc);
    float val = (lane == 0) ? xs[wv][0] : acc;
    h0[(size_t)bt * NFILT + lane] = logf(val + 1e-10f);
  }
}

// ---------- kernel 3: fp32 GEMM, 128x64 tile, 8x4 micro, scalar fmac ----------
// REVERTED to the proven-best R14 form. The R15 pk_fma variant regressed
// ~150 us: the row-pairing needed ~16 v_mov per kk (hp packing + w broadcast),
// eating the packed-FMA issue saving. Scalar fmac reads LDS values directly
// as operands -- no repacking.
template <int K, int BK>
__global__ __launch_bounds__(256) void k_gemm(const float* __restrict__ Hm,   // [MTOT][K]
                                              const float* __restrict__ W,    // [2][256][K]
                                              const float* __restrict__ bih,  // [2][256]
                                              const float* __restrict__ bhh,  // [2][256]
                                              float* __restrict__ pre) {      // [2][MTOT][256]
  constexpr int BM = 128, BN = 64;
  __shared__ float Hs[BK][BM + 4];
  __shared__ float Ws[BK][BN + 4];
  const int d  = blockIdx.z;
  const int m0 = blockIdx.x * BM;
  const int g0 = blockIdx.y * BN;
  const int tid = threadIdx.x;
  const int tx = tid & 15, ty = tid >> 4;

  float acc[8][4];
#pragma unroll
  for (int r = 0; r < 8; ++r)
#pragma unroll
    for (int j = 0; j < 4; ++j) acc[r][j] = 0.f;

  for (int k0 = 0; k0 < K; k0 += BK) {
    constexpr int HL = BM * BK / 256;
#pragma unroll
    for (int i = 0; i < HL; ++i) {
      int flat = tid + i * 256;
      int r = flat / BK, kk = flat - r * BK;
      Hs[kk][r] = Hm[(size_t)(m0 + r) * K + k0 + kk];
    }
    constexpr int WL = BN * BK / 256;
#pragma unroll
    for (int i = 0; i < WL; ++i) {
      int flat = tid + i * 256;
      int r = flat / BK, kk = flat - r * BK;
      Ws[kk][r] = W[((size_t)d * GATES + g0 + r) * K + k0 + kk];
    }
    __syncthreads();
#pragma unroll
    for (int kk = 0; kk < BK; ++kk) {
      const float4 wv  = *(const float4*)&Ws[kk][tx * 4];
      const float4 hv0 = *(const float4*)&Hs[kk][ty * 8];
      const float4 hv1 = *(const float4*)&Hs[kk][ty * 8 + 4];
      const float hr[8] = {hv0.x, hv0.y, hv0.z, hv0.w, hv1.x, hv1.y, hv1.z, hv1.w};
#pragma unroll
      for (int r = 0; r < 8; ++r) {
        acc[r][0] = fmaf(hr[r], wv.x, acc[r][0]);
        acc[r][1] = fmaf(hr[r], wv.y, acc[r][1]);
        acc[r][2] = fmaf(hr[r], wv.z, acc[r][2]);
        acc[r][3] = fmaf(hr[r], wv.w, acc[r][3]);
      }
    }
    __syncthreads();
  }

  const int gcol = g0 + tx * 4;
  const float4 bi = *(const float4*)&bih[d * GATES + gcol];
  const float4 bh = *(const float4*)&bhh[d * GATES + gcol];
  const float bx = bi.x + bh.x, by = bi.y + bh.y, bz = bi.z + bh.z, bw = bi.w + bh.w;
#pragma unroll
  for (int r = 0; r < 8; ++r) {
    size_t m = (size_t)(m0 + ty * 8 + r);
    float4 o = {acc[r][0] + bx, acc[r][1] + by, acc[r][2] + bz, acc[r][3] + bw};
    *(float4*)&pre[((size_t)d * MTOT + m) * GATES + gcol] = o;
  }
}

// ---------- kernel 4: recurrent LSTM, quad-per-unit, pk_fma matvec ----------
// VERBATIM round-15 configuration (proven 770 us/dispatch, VGPR 132):
//  * 4 waves/block, 1 wave/SIMD, waves_per_eu(1,1) + "+v" pin -> weights
//    VGPR-resident as float2 pairs; matvec = 32 v_pk_fma_f32 (8-deep chains).
//  * quad DPP butterfly completes gate sums in-register; ONE activation/lane
//    (sigma/tanh unified); 4 DPP quad broadcasts; pre added post-butterfly.
//  * parity double-buffered hs; raw asm "lgkmcnt(0); s_barrier" (no vmcnt
//    drain -> 4-deep HBM prefetch in flight). ONE LDS round-trip + ONE
//    barrier per step.
__global__ __attribute__((amdgpu_waves_per_eu(1, 1)))
__launch_bounds__(256) void k_lstmq(const float* __restrict__ pre, // [2][B*T][256]
                                    const float* __restrict__ whh, // [2][256][64]
                                    float* __restrict__ hout,      // [B][T][128]
                                    float* __restrict__ out,       // [B][128]
                                    int final_layer) {
  const int b   = blockIdx.x;
  const int d   = blockIdx.y;
  const int tid = threadIdx.x;
  const int wl  = tid >> 6;          // wave 0..3
  const int l   = tid & 63;
  const int uu  = wl * 16 + (l >> 2); // hidden unit owned by this quad
  const int p   = l & 3;              // k-slice / gate index
  const int p16 = p * 16;

  __shared__ __align__(16) float hs[2][HID];   // parity double-buffered h

  // weights as pairs: wp[q][i] = (W[d][q*64+uu][16p+2i], W[d][q*64+uu][16p+2i+1])
  float2v wp[4][8];
#pragma unroll
  for (int q = 0; q < 4; ++q) {
    const float4* wr = (const float4*)(whh + ((size_t)d * GATES + q * HID + uu) * HID + p16);
#pragma unroll
    for (int c2 = 0; c2 < 4; ++c2) {
      const float4 t4 = wr[c2];
      wp[q][2 * c2].x     = t4.x; wp[q][2 * c2].y     = t4.y;
      wp[q][2 * c2 + 1].x = t4.z; wp[q][2 * c2 + 1].y = t4.w;
    }
  }
#pragma unroll
  for (int q = 0; q < 4; ++q)
#pragma unroll
    for (int i = 0; i < 8; ++i) asm volatile("" : "+v"(wp[q][i]));  // pin resident

  // per-lane activation constants: gate 2 (p==2) is tanh = 2*sigm(2x)-1
  const float sA = (p == 2) ? 2.f : 1.f;   // input scale
  const float aA = (p == 2) ? 2.f : 1.f;   // output scale
  const float aB = (p == 2) ? -1.f : 0.f;  // output bias
  const bool  p1 = (p & 1) != 0;
  const bool  p2 = (p & 2) != 0;

  if (tid < HID) { hs[0][tid] = 0.f; hs[1][tid] = 0.f; }
  float c = 0.f, sum = 0.f;
  __syncthreads();   // one-time full barrier

  const int t0 = d ? (TT - 1) : 0;
  const int dt = d ? -1 : 1;
  const float* pp = pre + ((size_t)d * MTOT + (size_t)b * TT + t0) * GATES + (p * HID + uu);
  const ptrdiff_t pstr = (ptrdiff_t)dt * GATES;

  float pf0 = pp[0], pf1 = pp[pstr], pf2 = pp[pstr * 2], pf3 = pp[pstr * 3];

#define GDOT(Q)                                                                 \
  ({ float2v acc_ = {0.f, 0.f};                                                 \
     acc_ = pk_fma(A0, wp[Q][0], acc_);                                         \
     acc_ = pk_fma(A1, wp[Q][1], acc_);                                         \
     acc_ = pk_fma(B0, wp[Q][2], acc_);                                         \
     acc_ = pk_fma(B1, wp[Q][3], acc_);                                         \
     acc_ = pk_fma(C0, wp[Q][4], acc_);                                         \
     acc_ = pk_fma(C1, wp[Q][5], acc_);                                         \
     acc_ = pk_fma(D0, wp[Q][6], acc_);                                         \
     acc_ = pk_fma(D1, wp[Q][7], acc_);                                         \
     acc_.x + acc_.y; })

#define LSTM_STEP(TK, PAR, PF)                                                  \
  do {                                                                          \
    const float4* h4 = (const float4*)&hs[PAR][p16];                            \
    const float4 hA = h4[0], hB = h4[1], hC = h4[2], hD = h4[3];                \
    float2v A0, A1, B0, B1, C0, C1, D0, D1;                                     \
    A0.x = hA.x; A0.y = hA.y; A1.x = hA.z; A1.y = hA.w;                         \
    B0.x = hB.x; B0.y = hB.y; B1.x = hB.z; B1.y = hB.w;                         \
    C0.x = hC.x; C0.y = hC.y; C1.x = hC.z; C1.y = hC.w;                         \
    D0.x = hD.x; D0.y = hD.y; D1.x = hD.z; D1.y = hD.w;                         \
    float a0 = GDOT(0);                                                         \
    float a1 = GDOT(1);                                                         \
    float a2 = GDOT(2);                                                         \
    float a3 = GDOT(3);                                                         \
    a0 = bfly2(bfly1(a0)); a1 = bfly2(bfly1(a1));                               \
    a2 = bfly2(bfly1(a2)); a3 = bfly2(bfly1(a3));                               \
    const float t02 = p2 ? a2 : a0;                                             \
    const float t13 = p2 ? a3 : a1;                                             \
    const float zsel = (p1 ? t13 : t02) + (PF);                                 \
    const float act = fmaf(sigm(zsel * sA), aA, aB);                            \
    const float ig = QB(act, 0x00), fg = QB(act, 0x55);                         \
    const float gg = QB(act, 0xAA), og = QB(act, 0xFF);                         \
    c = fmaf(fg, c, ig * gg);                                                   \
    const float tc = fmaf(sigm(2.f * c), 2.f, -1.f);                            \
    const float hvv = og * tc;                                                  \
    if (p == 0) hs[(PAR) ^ 1][uu] = hvv;                                        \
    asm volatile("s_waitcnt lgkmcnt(0)\n\ts_barrier" ::: "memory");             \
    if (final_layer) sum += hvv;                                                \
    else if (p == 0)                                                            \
      hout[((size_t)b * TT + (size_t)(t0 + dt * (TK))) * (2 * HID) + d * HID + uu] = hvv; \
  } while (0)

  for (int t = 0; t < TT; t += 4) {
    LSTM_STEP(t + 0, 0, pf0);
    { int ip = t + 4; if (ip >= TT) ip = 0; pf0 = pp[pstr * (ptrdiff_t)ip]; }
    LSTM_STEP(t + 1, 1, pf1);
    { int ip = t + 5; if (ip >= TT) ip = 0; pf1 = pp[pstr * (ptrdiff_t)ip]; }
    LSTM_STEP(t + 2, 0, pf2);
    { int ip = t + 6; if (ip >= TT) ip = 0; pf2 = pp[pstr * (ptrdiff_t)ip]; }
    LSTM_STEP(t + 3, 1, pf3);
    { int ip = t + 7; if (ip >= TT) ip = 0; pf3 = pp[pstr * (ptrdiff_t)ip]; }
  }
#undef LSTM_STEP
#undef GDOT

  if (final_layer && p == 0) out[b * (2 * HID) + d * HID + uu] = sum * (1.0f / (float)TT);
}

// ---------- launch ----------
extern "C" void kernel_launch(void* const* d_in, const int* in_sizes, int n_in,
                              void* d_out, int out_size, void* d_ws, size_t ws_size,
                              hipStream_t stream) {
  const float* x         = (const float*)d_in[0];
  const float* binpoints = (const float*)d_in[1];
  const float* w_ih[3] = {(const float*)d_in[2], (const float*)d_in[6],  (const float*)d_in[10]};
  const float* w_hh[3] = {(const float*)d_in[3], (const float*)d_in[7],  (const float*)d_in[11]};
  const float* b_ih[3] = {(const float*)d_in[4], (const float*)d_in[8],  (const float*)d_in[12]};
  const float* b_hh[3] = {(const float*)d_in[5], (const float*)d_in[9],  (const float*)d_in[13]};
  float* out = (float*)d_out;

  // workspace layout (~349 MB):
  //   pre  : 2*MTOT*256 f32 = 262,144,000 B
  //   Hbuf : MTOT*128 f32   =  65,536,000 B
  //   h0   : MTOT*40 f32    =  20,480,000 B
  //   fbank: 40*257 f32, lohi: 80 i32
  float* pre   = (float*)d_ws;
  float* Hbuf  = pre  + (size_t)2 * MTOT * GATES;
  float* h0    = Hbuf + (size_t)MTOT * 128;
  float* fbank = h0   + (size_t)MTOT * NFILT;
  int*   lohi  = (int*)(fbank + NFILT * NBINS);

  k_fbank<<<1, 256, 0, stream>>>(binpoints, fbank, lohi);
  k_feat<<<MTOT / 4, 256, 0, stream>>>(x, fbank, lohi, h0);

  // layer 0 (K=40)
  k_gemm<40, 40><<<dim3(MTOT / 128, GATES / 64, 2), 256, 0, stream>>>(h0, w_ih[0], b_ih[0], b_hh[0], pre);
  k_lstmq<<<dim3(BB, 2), 256, 0, stream>>>(pre, w_hh[0], Hbuf, out, 0);

  // layer 1 (K=128)
  k_gemm<128, 32><<<dim3(MTOT / 128, GATES / 64, 2), 256, 0, stream>>>(Hbuf, w_ih[1], b_ih[1], b_hh[1], pre);
  k_lstmq<<<dim3(BB, 2), 256, 0, stream>>>(pre, w_hh[1], Hbuf, out, 0);

  // layer 2 (K=128)
  k_gemm<128, 32><<<dim3(MTOT / 128, GATES / 64, 2), 256, 0, stream>>>(Hbuf, w_ih[2], b_ih[2], b_hh[2], pre);
  k_lstmq<<<dim3(BB, 2), 256, 0, stream>>>(pre, w_hh[2], Hbuf, out, 1);
}

// Round 17
// 2822.624 us; speedup vs baseline: 1.0927x; 1.0300x over previous
//
#include <hip/hip_runtime.h>
#include <cstdint>
#include <cstddef>

#define NFILT 40
#define NBINS 257
#define HID   64
#define BB    64      // batch
#define TT    2000    // time
#define GATES 256     // 4*HID
#define MTOT  (BB*TT) // 128000 rows

typedef float float2v __attribute__((ext_vector_type(2)));
typedef float float4v __attribute__((ext_vector_type(4)));

// packed dual-FMA: one VOP3P instruction = 2 independent fp32 FMAs (elementwise)
__device__ __forceinline__ float2v pk_fma(float2v a, float2v b, float2v c) {
  asm("v_pk_fma_f32 %0, %1, %2, %0" : "+v"(c) : "v"(a), "v"(b));
  return c;
}
// broadcast variants via op_sel: both result halves read the SAME 32-bit reg of
// the h pair (lo for _bl, hi for _bh) -> scalar-times-pair with ZERO repack movs.
// op_sel[i] picks the source reg for the LO half, op_sel_hi[i] for the HI half.
__device__ __forceinline__ float2v pk_fma_bl(float2v h2, float2v w2, float2v c) {
  asm("v_pk_fma_f32 %0, %1, %2, %0 op_sel:[0,0,0] op_sel_hi:[0,1,1]"
      : "+v"(c) : "v"(h2), "v"(w2));
  return c;
}
__device__ __forceinline__ float2v pk_fma_bh(float2v h2, float2v w2, float2v c) {
  asm("v_pk_fma_f32 %0, %1, %2, %0 op_sel:[1,0,0] op_sel_hi:[1,1,1]"
      : "+v"(c) : "v"(h2), "v"(w2));
  return c;
}

// ---------- activations ----------
__device__ __forceinline__ float sigm(float x) {
  return 1.0f / (1.0f + __expf(-x));
}

// quad butterfly via DPP (VALU pipe, no LDS) (numerically verified R5/R11/R12)
__device__ __forceinline__ float bfly1(float x) {
  int i = __builtin_amdgcn_mov_dpp(__float_as_int(x), 0xB1, 0xF, 0xF, true); // quad_perm [1,0,3,2]
  return x + __int_as_float(i);
}
__device__ __forceinline__ float bfly2(float x) {
  int i = __builtin_amdgcn_mov_dpp(__float_as_int(x), 0x4E, 0xF, 0xF, true); // quad_perm [2,3,0,1]
  return x + __int_as_float(i);
}
// quad broadcast: every lane gets lane q's value (quad_perm [q,q,q,q])
#define QB(x, ctrl) __int_as_float(__builtin_amdgcn_mov_dpp(__float_as_int(x), (ctrl), 0xF, 0xF, true))

// ---------- kernel 1: build fbank (40x257) + per-filter support bounds ----------
__global__ void k_fbank(const float* __restrict__ binpoints,
                        float* __restrict__ fbank,
                        int* __restrict__ lohi /*[2*NFILT]*/) {
  __shared__ float b[NFILT + 2];
  int tid = threadIdx.x;
  if (tid < NFILT + 2) b[tid] = binpoints[tid];
  __syncthreads();
  if (tid < NFILT) {
    if (tid == NFILT - 1) { lohi[tid] = 0; lohi[NFILT + tid] = 0; }
    else {
      int lo = (int)floorf(b[tid]);
      int hi = (int)floorf(b[tid + 2]);
      if (lo < 0) lo = 0;
      if (hi > NBINS) hi = NBINS;
      lohi[tid] = lo; lohi[NFILT + tid] = hi;
    }
  }
  for (int idx = tid; idx < NFILT * NBINS; idx += blockDim.x) {
    int f = idx / NBINS, i = idx - f * NBINS;
    float bj = b[f], bj1 = b[f + 1], bj2 = b[f + 2];
    float fb0 = floorf(bj), fb1 = floorf(bj1), fb2 = floorf(bj2);
    float fi = (float)i;
    bool rise = (fi >= fb0) && (fi < fb1);
    bool fall = (fi >= fb1) && (fi < fb2);
    float d1 = bj1 - bj;  d1 = (d1 > 0.f) ? d1 : 1.f;
    float d2 = bj2 - bj1; d2 = (d2 > 0.f) ? d2 : 1.f;
    float rv = (fi - bj)  / (d1 * d1);
    float fv = (bj2 - fi) / (d2 * d2);
    float v = fall ? fv : (rise ? rv : 0.f);
    if (f == NFILT - 1) v = 0.f;
    fbank[idx] = v;
  }
}

// ---------- kernel 2: featurize, 4 rows per 256-thread block (one wave each) ----------
__global__ __launch_bounds__(256) void k_feat(const float* __restrict__ x,
                                              const float* __restrict__ fbank,
                                              const int* __restrict__ lohi,
                                              float* __restrict__ h0) {
  const int wv   = threadIdx.x >> 6;
  const int lane = threadIdx.x & 63;
  const int bt   = blockIdx.x * 4 + wv;
  __shared__ float xs[4][NBINS];
  const float* xr = x + (size_t)bt * NBINS;
  for (int i = lane; i < NBINS; i += 64) xs[wv][i] = xr[i];
  __syncthreads();
  if (lane < NFILT) {
    float acc = 0.f;
    int lo = lohi[lane], hi = lohi[NFILT + lane];
    for (int i = lo; i < hi; ++i) acc = fmaf(xs[wv][i], fbank[lane * NBINS + i], acc);
    float val = (lane == 0) ? xs[wv][0] : acc;
    h0[(size_t)bt * NFILT + lane] = logf(val + 1e-10f);
  }
}

// ---------- kernel 3: fp32 GEMM, 128x64 tile, 8x4 micro, op_sel pk_fma inner loop ----------
// Inner loop: 16 v_pk_fma_f32 per kk (vs 32 fmac) with ZERO repack movs -- h pairs
// and w pairs fall directly out of the ds_read_b128 result registers; the per-row
// h broadcast is done by op_sel (both halves read the same pair register).
// Column accumulation order per output is unchanged -> bit-exact vs R16.
// Staging: float4 global loads (4 load insts/thread/tile instead of 16).
template <int K, int BK>
__global__ __launch_bounds__(256) void k_gemm(const float* __restrict__ Hm,   // [MTOT][K]
                                              const float* __restrict__ W,    // [2][256][K]
                                              const float* __restrict__ bih,  // [2][256]
                                              const float* __restrict__ bhh,  // [2][256]
                                              float* __restrict__ pre) {      // [2][MTOT][256]
  constexpr int BM = 128, BN = 64;
  __shared__ float Hs[BK][BM + 4];
  __shared__ float Ws[BK][BN + 4];
  const int d  = blockIdx.z;
  const int m0 = blockIdx.x * BM;
  const int g0 = blockIdx.y * BN;
  const int tid = threadIdx.x;
  const int tx = tid & 15, ty = tid >> 4;

  float2v acc2[8][2];   // [row r][col pair jp]: lo = col 2jp+... (jp0: cols 0,1; jp1: cols 2,3)
#pragma unroll
  for (int r = 0; r < 8; ++r) {
    acc2[r][0] = (float2v){0.f, 0.f};
    acc2[r][1] = (float2v){0.f, 0.f};
  }

  for (int k0 = 0; k0 < K; k0 += BK) {
    // H staging: float4 loads (BK divisible by 4; rows of Hm 16B-aligned at kk%4==0)
    constexpr int HE4 = BM * BK / 4;
#pragma unroll
    for (int i = 0; i < (HE4 + 255) / 256; ++i) {
      int f4 = tid + i * 256;
      if ((HE4 % 256 == 0) || (f4 < HE4)) {
        int e = f4 * 4, r = e / BK, kk = e - r * BK;
        const float4 v = *(const float4*)&Hm[(size_t)(m0 + r) * K + k0 + kk];
        Hs[kk][r] = v.x; Hs[kk + 1][r] = v.y; Hs[kk + 2][r] = v.z; Hs[kk + 3][r] = v.w;
      }
    }
    constexpr int WE4 = BN * BK / 4;
#pragma unroll
    for (int i = 0; i < (WE4 + 255) / 256; ++i) {
      int f4 = tid + i * 256;
      if ((WE4 % 256 == 0) || (f4 < WE4)) {
        int e = f4 * 4, r = e / BK, kk = e - r * BK;
        const float4 v = *(const float4*)&W[((size_t)d * GATES + g0 + r) * K + k0 + kk];
        Ws[kk][r] = v.x; Ws[kk + 1][r] = v.y; Ws[kk + 2][r] = v.z; Ws[kk + 3][r] = v.w;
      }
    }
    __syncthreads();
#pragma unroll
    for (int kk = 0; kk < BK; ++kk) {
      const float4v wv  = *(const float4v*)&Ws[kk][tx * 4];
      const float4v hv0 = *(const float4v*)&Hs[kk][ty * 8];
      const float4v hv1 = *(const float4v*)&Hs[kk][ty * 8 + 4];
      const float2v w01 = __builtin_shufflevector(wv, wv, 0, 1);
      const float2v w23 = __builtin_shufflevector(wv, wv, 2, 3);
      float2v hp[4];
      hp[0] = __builtin_shufflevector(hv0, hv0, 0, 1);
      hp[1] = __builtin_shufflevector(hv0, hv0, 2, 3);
      hp[2] = __builtin_shufflevector(hv1, hv1, 0, 1);
      hp[3] = __builtin_shufflevector(hv1, hv1, 2, 3);
#pragma unroll
      for (int rp = 0; rp < 4; ++rp) {
        acc2[2 * rp + 0][0] = pk_fma_bl(hp[rp], w01, acc2[2 * rp + 0][0]);
        acc2[2 * rp + 0][1] = pk_fma_bl(hp[rp], w23, acc2[2 * rp + 0][1]);
        acc2[2 * rp + 1][0] = pk_fma_bh(hp[rp], w01, acc2[2 * rp + 1][0]);
        acc2[2 * rp + 1][1] = pk_fma_bh(hp[rp], w23, acc2[2 * rp + 1][1]);
      }
    }
    __syncthreads();
  }

  const int gcol = g0 + tx * 4;
  const float4 bi = *(const float4*)&bih[d * GATES + gcol];
  const float4 bh = *(const float4*)&bhh[d * GATES + gcol];
  const float bx = bi.x + bh.x, by = bi.y + bh.y, bz = bi.z + bh.z, bw = bi.w + bh.w;
#pragma unroll
  for (int r = 0; r < 8; ++r) {
    size_t m = (size_t)(m0 + ty * 8 + r);
    float4 o = {acc2[r][0].x + bx, acc2[r][0].y + by, acc2[r][1].x + bz, acc2[r][1].y + bw};
    *(float4*)&pre[((size_t)d * MTOT + m) * GATES + gcol] = o;
  }
}

// ---------- kernel 4: recurrent LSTM, quad-per-unit, pk_fma matvec ----------
// VERBATIM round-15/16 configuration (proven 750-770 us/dispatch, VGPR 132):
//  * 4 waves/block, 1 wave/SIMD, waves_per_eu(1,1) + "+v" pin -> weights
//    VGPR-resident as float2 pairs; matvec = 32 v_pk_fma_f32 (8-deep chains).
//  * quad DPP butterfly completes gate sums in-register; ONE activation/lane
//    (sigma/tanh unified); 4 DPP quad broadcasts; pre added post-butterfly.
//  * parity double-buffered hs; raw asm "lgkmcnt(0); s_barrier" (no vmcnt
//    drain -> 4-deep HBM prefetch in flight). ONE LDS round-trip + ONE
//    barrier per step.
__global__ __attribute__((amdgpu_waves_per_eu(1, 1)))
__launch_bounds__(256) void k_lstmq(const float* __restrict__ pre, // [2][B*T][256]
                                    const float* __restrict__ whh, // [2][256][64]
                                    float* __restrict__ hout,      // [B][T][128]
                                    float* __restrict__ out,       // [B][128]
                                    int final_layer) {
  const int b   = blockIdx.x;
  const int d   = blockIdx.y;
  const int tid = threadIdx.x;
  const int wl  = tid >> 6;          // wave 0..3
  const int l   = tid & 63;
  const int uu  = wl * 16 + (l >> 2); // hidden unit owned by this quad
  const int p   = l & 3;              // k-slice / gate index
  const int p16 = p * 16;

  __shared__ __align__(16) float hs[2][HID];   // parity double-buffered h

  // weights as pairs: wp[q][i] = (W[d][q*64+uu][16p+2i], W[d][q*64+uu][16p+2i+1])
  float2v wp[4][8];
#pragma unroll
  for (int q = 0; q < 4; ++q) {
    const float4* wr = (const float4*)(whh + ((size_t)d * GATES + q * HID + uu) * HID + p16);
#pragma unroll
    for (int c2 = 0; c2 < 4; ++c2) {
      const float4 t4 = wr[c2];
      wp[q][2 * c2].x     = t4.x; wp[q][2 * c2].y     = t4.y;
      wp[q][2 * c2 + 1].x = t4.z; wp[q][2 * c2 + 1].y = t4.w;
    }
  }
#pragma unroll
  for (int q = 0; q < 4; ++q)
#pragma unroll
    for (int i = 0; i < 8; ++i) asm volatile("" : "+v"(wp[q][i]));  // pin resident

  // per-lane activation constants: gate 2 (p==2) is tanh = 2*sigm(2x)-1
  const float sA = (p == 2) ? 2.f : 1.f;   // input scale
  const float aA = (p == 2) ? 2.f : 1.f;   // output scale
  const float aB = (p == 2) ? -1.f : 0.f;  // output bias
  const bool  p1 = (p & 1) != 0;
  const bool  p2 = (p & 2) != 0;

  if (tid < HID) { hs[0][tid] = 0.f; hs[1][tid] = 0.f; }
  float c = 0.f, sum = 0.f;
  __syncthreads();   // one-time full barrier

  const int t0 = d ? (TT - 1) : 0;
  const int dt = d ? -1 : 1;
  const float* pp = pre + ((size_t)d * MTOT + (size_t)b * TT + t0) * GATES + (p * HID + uu);
  const ptrdiff_t pstr = (ptrdiff_t)dt * GATES;

  float pf0 = pp[0], pf1 = pp[pstr], pf2 = pp[pstr * 2], pf3 = pp[pstr * 3];

#define GDOT(Q)                                                                 \
  ({ float2v acc_ = {0.f, 0.f};                                                 \
     acc_ = pk_fma(A0, wp[Q][0], acc_);                                         \
     acc_ = pk_fma(A1, wp[Q][1], acc_);                                         \
     acc_ = pk_fma(B0, wp[Q][2], acc_);                                         \
     acc_ = pk_fma(B1, wp[Q][3], acc_);                                         \
     acc_ = pk_fma(C0, wp[Q][4], acc_);                                         \
     acc_ = pk_fma(C1, wp[Q][5], acc_);                                         \
     acc_ = pk_fma(D0, wp[Q][6], acc_);                                         \
     acc_ = pk_fma(D1, wp[Q][7], acc_);                                         \
     acc_.x + acc_.y; })

#define LSTM_STEP(TK, PAR, PF)                                                  \
  do {                                                                          \
    const float4* h4 = (const float4*)&hs[PAR][p16];                            \
    const float4 hA = h4[0], hB = h4[1], hC = h4[2], hD = h4[3];                \
    float2v A0, A1, B0, B1, C0, C1, D0, D1;                                     \
    A0.x = hA.x; A0.y = hA.y; A1.x = hA.z; A1.y = hA.w;                         \
    B0.x = hB.x; B0.y = hB.y; B1.x = hB.z; B1.y = hB.w;                         \
    C0.x = hC.x; C0.y = hC.y; C1.x = hC.z; C1.y = hC.w;                         \
    D0.x = hD.x; D0.y = hD.y; D1.x = hD.z; D1.y = hD.w;                         \
    float a0 = GDOT(0);                                                         \
    float a1 = GDOT(1);                                                         \
    float a2 = GDOT(2);                                                         \
    float a3 = GDOT(3);                                                         \
    a0 = bfly2(bfly1(a0)); a1 = bfly2(bfly1(a1));                               \
    a2 = bfly2(bfly1(a2)); a3 = bfly2(bfly1(a3));                               \
    const float t02 = p2 ? a2 : a0;                                             \
    const float t13 = p2 ? a3 : a1;                                             \
    const float zsel = (p1 ? t13 : t02) + (PF);                                 \
    const float act = fmaf(sigm(zsel * sA), aA, aB);                            \
    const float ig = QB(act, 0x00), fg = QB(act, 0x55);                         \
    const float gg = QB(act, 0xAA), og = QB(act, 0xFF);                         \
    c = fmaf(fg, c, ig * gg);                                                   \
    const float tc = fmaf(sigm(2.f * c), 2.f, -1.f);                            \
    const float hvv = og * tc;                                                  \
    if (p == 0) hs[(PAR) ^ 1][uu] = hvv;                                        \
    asm volatile("s_waitcnt lgkmcnt(0)\n\ts_barrier" ::: "memory");             \
    if (final_layer) sum += hvv;                                                \
    else if (p == 0)                                                            \
      hout[((size_t)b * TT + (size_t)(t0 + dt * (TK))) * (2 * HID) + d * HID + uu] = hvv; \
  } while (0)

  for (int t = 0; t < TT; t += 4) {
    LSTM_STEP(t + 0, 0, pf0);
    { int ip = t + 4; if (ip >= TT) ip = 0; pf0 = pp[pstr * (ptrdiff_t)ip]; }
    LSTM_STEP(t + 1, 1, pf1);
    { int ip = t + 5; if (ip >= TT) ip = 0; pf1 = pp[pstr * (ptrdiff_t)ip]; }
    LSTM_STEP(t + 2, 0, pf2);
    { int ip = t + 6; if (ip >= TT) ip = 0; pf2 = pp[pstr * (ptrdiff_t)ip]; }
    LSTM_STEP(t + 3, 1, pf3);
    { int ip = t + 7; if (ip >= TT) ip = 0; pf3 = pp[pstr * (ptrdiff_t)ip]; }
  }
#undef LSTM_STEP
#undef GDOT

  if (final_layer && p == 0) out[b * (2 * HID) + d * HID + uu] = sum * (1.0f / (float)TT);
}

// ---------- launch ----------
extern "C" void kernel_launch(void* const* d_in, const int* in_sizes, int n_in,
                              void* d_out, int out_size, void* d_ws, size_t ws_size,
                              hipStream_t stream) {
  const float* x         = (const float*)d_in[0];
  const float* binpoints = (const float*)d_in[1];
  const float* w_ih[3] = {(const float*)d_in[2], (const float*)d_in[6],  (const float*)d_in[10]};
  const float* w_hh[3] = {(const float*)d_in[3], (const float*)d_in[7],  (const float*)d_in[11]};
  const float* b_ih[3] = {(const float*)d_in[4], (const float*)d_in[8],  (const float*)d_in[12]};
  const float* b_hh[3] = {(const float*)d_in[5], (const float*)d_in[9],  (const float*)d_in[13]};
  float* out = (float*)d_out;

  // workspace layout (~349 MB):
  //   pre  : 2*MTOT*256 f32 = 262,144,000 B
  //   Hbuf : MTOT*128 f32   =  65,536,000 B
  //   h0   : MTOT*40 f32    =  20,480,000 B
  //   fbank: 40*257 f32, lohi: 80 i32
  float* pre   = (float*)d_ws;
  float* Hbuf  = pre  + (size_t)2 * MTOT * GATES;
  float* h0    = Hbuf + (size_t)MTOT * 128;
  float* fbank = h0   + (size_t)MTOT * NFILT;
  int*   lohi  = (int*)(fbank + NFILT * NBINS);

  k_fbank<<<1, 256, 0, stream>>>(binpoints, fbank, lohi);
  k_feat<<<MTOT / 4, 256, 0, stream>>>(x, fbank, lohi, h0);

  // layer 0 (K=40)
  k_gemm<40, 40><<<dim3(MTOT / 128, GATES / 64, 2), 256, 0, stream>>>(h0, w_ih[0], b_ih[0], b_hh[0], pre);
  k_lstmq<<<dim3(BB, 2), 256, 0, stream>>>(pre, w_hh[0], Hbuf, out, 0);

  // layer 1 (K=128)
  k_gemm<128, 32><<<dim3(MTOT / 128, GATES / 64, 2), 256, 0, stream>>>(Hbuf, w_ih[1], b_ih[1], b_hh[1], pre);
  k_lstmq<<<dim3(BB, 2), 256, 0, stream>>>(pre, w_hh[1], Hbuf, out, 0);

  // layer 2 (K=128)
  k_gemm<128, 32><<<dim3(MTOT / 128, GATES / 64, 2), 256, 0, stream>>>(Hbuf, w_ih[2], b_ih[2], b_hh[2], pre);
  k_lstmq<<<dim3(BB, 2), 256, 0, stream>>>(pre, w_hh[2], Hbuf, out, 1);
}